// Round 2
// baseline (497.318 us; speedup 1.0000x reference)
//
#include <hip/hip_runtime.h>
#include <math.h>

#define N_NODES 50000
#define N_EDGES 1600000
#define NB      391          // ceil(50000/128) buckets of 128 nodes

typedef __attribute__((ext_vector_type(2))) float v2f;
typedef __attribute__((ext_vector_type(4))) float f32x4;
typedef __attribute__((ext_vector_type(8))) __bf16 bf16x8;

__device__ __forceinline__ float lrelu02(float x) { return x > 0.f ? x : 0.2f * x; }
__device__ __forceinline__ float elu1(float x)    { return x > 0.f ? x : __expf(x) - 1.f; }

// bf16 helpers (RNE pack)
__device__ __forceinline__ unsigned short f2bf(float f) {
    unsigned int u = __float_as_uint(f);
    return (unsigned short)((u + 0x7fffu + ((u >> 16) & 1u)) >> 16);
}
__device__ __forceinline__ float bf2f(unsigned short s) {
    return __uint_as_float((unsigned int)s << 16);
}
__device__ __forceinline__ float2 bfp2(unsigned int u) {
    float2 r;
    r.x = __uint_as_float(u << 16);
    r.y = __uint_as_float(u & 0xffff0000u);
    return r;
}

union BF8U { unsigned short u[8]; bf16x8 v; };
__device__ __forceinline__ bf16x8 cvt8(float4 a, float4 b) {
    BF8U r;
    r.u[0] = f2bf(a.x); r.u[1] = f2bf(a.y); r.u[2] = f2bf(a.z); r.u[3] = f2bf(a.w);
    r.u[4] = f2bf(b.x); r.u[5] = f2bf(b.y); r.u[6] = f2bf(b.z); r.u[7] = f2bf(b.w);
    return r.v;
}

// ------- GEMM layers 1/2 (FOUT=64) via MFMA bf16, fused attention logits -------
template<int FIN>
__global__ __launch_bounds__(256) void gemm_al_kernel(const float* __restrict__ x,
                               const float* __restrict__ W,
                               const float* __restrict__ a_s, const float* __restrict__ a_d,
                               unsigned short* __restrict__ h,
                               float* __restrict__ al_s, float* __restrict__ al_d) {
    constexpr int KS = FIN / 32;
    __shared__ alignas(16) unsigned short Wl[KS * 64 * 32];   // bf16, FIN*64*2 B
    __shared__ alignas(16) unsigned short ot[64][64];         // block output, bf16
    const int tid = threadIdx.x;
    for (int i = tid; i < FIN * 64; i += 256) {
        int ks = i >> 11;            // / (64*32)
        int rem = i & 2047;
        int c = rem >> 5, r = rem & 31;
        Wl[i] = f2bf(W[(ks * 32 + r) * 64 + c]);
    }
    __syncthreads();

    const int wv = tid >> 6, l = tid & 63;
    const int m = l & 15, g = l >> 4;
    const int n0 = blockIdx.x * 64;
    int row = n0 + wv * 16 + m;
    if (row > N_NODES - 1) row = N_NODES - 1;     // tail clamp; results discarded
    const float* xr = x + (size_t)row * FIN + g * 8;

    f32x4 acc[4] = {};   // 4 col-tiles of 16
#pragma unroll
    for (int ks = 0; ks < KS; ++ks) {
        float4 xa = *(const float4*)(xr + ks * 32);
        float4 xb = *(const float4*)(xr + ks * 32 + 4);
        bf16x8 af = cvt8(xa, xb);
        const unsigned short* wp = &Wl[ks * 2048 + g * 8];
#pragma unroll
        for (int t = 0; t < 4; ++t) {
            bf16x8 bf = *(const bf16x8*)(wp + (t * 16 + m) * 32);
            acc[t] = __builtin_amdgcn_mfma_f32_16x16x32_bf16(af, bf, acc[t], 0, 0, 0);
        }
    }
    // C/D layout: col = lane&15, row = (lane>>4)*4 + reg  [HW-verified]
#pragma unroll
    for (int t = 0; t < 4; ++t)
#pragma unroll
        for (int j = 0; j < 4; ++j)
            ot[wv * 16 + g * 4 + j][t * 16 + m] = f2bf(acc[t][j]);
    __syncthreads();

    int vrows = N_NODES - n0; if (vrows > 64) vrows = 64;
    {   // node-major coalesced h writeout (bf16 pairs as uints)
        unsigned int* ph = (unsigned int*)(h + (size_t)n0 * 64);
        for (int i = tid; i < vrows * 32; i += 256) {
            int r = i >> 5, c = i & 31;
            ph[i] = *(const unsigned int*)&ot[r][c * 2];
        }
    }
    // fused al_s / al_d: 64 nodes x 4 heads = 256 threads
    {
        int node = tid >> 2, hd = tid & 3;
        if (node < vrows) {
            const float* as = a_s + hd * 16;
            const float* ad = a_d + hd * 16;
            float s1 = 0.f, s2 = 0.f;
#pragma unroll
            for (int c = 0; c < 16; c += 2) {
                unsigned int q = *(const unsigned int*)&ot[node][hd * 16 + c];
                float2 p = bfp2(q);
                s1 = fmaf(p.x, as[c], s1);     s2 = fmaf(p.x, ad[c], s2);
                s1 = fmaf(p.y, as[c + 1], s1); s2 = fmaf(p.y, ad[c + 1], s2);
            }
            al_s[(n0 + node) * 4 + hd] = s1;
            al_d[(n0 + node) * 4 + hd] = s2;
        }
    }
}

// ------- L3 GEMM via MFMA: N=240 split into 3 col-blocks of 80 (5 tiles, 2 heads each) -------
__global__ __launch_bounds__(256) void gemm80_kernel(const float* __restrict__ x,
                              const float* __restrict__ W,
                              const float* __restrict__ a_s, const float* __restrict__ a_d,
                              unsigned int* __restrict__ h8,
                              float* __restrict__ al_s, float* __restrict__ al_d) {
    __shared__ alignas(16) unsigned short Wl[2 * 80 * 32];    // 10 KB
    __shared__ alignas(16) unsigned short ot[64][80];         // 10 KB
    const int tid = threadIdx.x;
    const int nb = blockIdx.x / 3, third = blockIdx.x % 3;
    const int cb = third * 80;
    for (int i = tid; i < 2 * 80 * 32; i += 256) {
        int ks = i / 2560;
        int rem = i - ks * 2560;
        int c = rem >> 5, r = rem & 31;
        Wl[i] = f2bf(W[(ks * 32 + r) * 240 + cb + c]);
    }
    __syncthreads();

    const int wv = tid >> 6, l = tid & 63;
    const int m = l & 15, g = l >> 4;
    const int n0 = nb * 64;
    int row = n0 + wv * 16 + m;
    if (row > N_NODES - 1) row = N_NODES - 1;
    const float* xr = x + (size_t)row * 64 + g * 8;

    f32x4 acc[5] = {};
#pragma unroll
    for (int ks = 0; ks < 2; ++ks) {
        float4 xa = *(const float4*)(xr + ks * 32);
        float4 xb = *(const float4*)(xr + ks * 32 + 4);
        bf16x8 af = cvt8(xa, xb);
        const unsigned short* wp = &Wl[ks * 2560 + g * 8];
#pragma unroll
        for (int t = 0; t < 5; ++t) {
            bf16x8 bf = *(const bf16x8*)(wp + (t * 16 + m) * 32);
            acc[t] = __builtin_amdgcn_mfma_f32_16x16x32_bf16(af, bf, acc[t], 0, 0, 0);
        }
    }
#pragma unroll
    for (int t = 0; t < 5; ++t)
#pragma unroll
        for (int j = 0; j < 4; ++j)
            ot[wv * 16 + g * 4 + j][t * 16 + m] = f2bf(acc[t][j]);
    __syncthreads();

    int vrows = N_NODES - n0; if (vrows > 64) vrows = 64;
    {   // fp8 writeout: this col-third owns 20 uints of each 64-uint row
        for (int i = tid; i < vrows * 20; i += 256) {
            int r = i / 20, c = i - r * 20;
            uint2 q = *(const uint2*)&ot[r][c * 4];
            float2 p0 = bfp2(q.x), p1 = bfp2(q.y);
            int lo = __builtin_amdgcn_cvt_pk_fp8_f32(p0.x, p0.y, 0, false);
            unsigned int packed = (unsigned int)__builtin_amdgcn_cvt_pk_fp8_f32(p1.x, p1.y, lo, true);
            h8[(size_t)(n0 + r) * 64 + cb / 4 + c] = packed;
        }
        if (third == 0) {  // zero the 4 pad uints per row
            for (int i = tid; i < vrows * 4; i += 256)
                h8[(size_t)(n0 + (i >> 2)) * 64 + 60 + (i & 3)] = 0;
        }
    }
    // al3 for the 2 heads of this col-third: 64 nodes x 2 heads = 128 threads
    for (int t = tid; t < vrows * 2; t += 256) {
        int node = t >> 1, hh = t & 1;
        int hd = third * 2 + hh;
        const unsigned short* rp = &ot[node][hh * 40];
        const float* as = a_s + hd * 40;
        const float* ad = a_d + hd * 40;
        float s1 = 0.f, s2 = 0.f;
#pragma unroll
        for (int c = 0; c < 40; c += 2) {
            unsigned int q = *(const unsigned int*)(rp + c);
            float2 p = bfp2(q);
            s1 = fmaf(p.x, as[c], s1);     s2 = fmaf(p.x, ad[c], s2);
            s1 = fmaf(p.y, as[c + 1], s1); s2 = fmaf(p.y, ad[c + 1], s2);
        }
        al_s[(n0 + node) * 6 + hd] = s1;
        al_d[(n0 + node) * 6 + hd] = s2;
    }
}

// ---------------- CSR build v2: direct atomic placement (no staging scatter) ----------------
// deg: int4-vectorized histogram over dst (50k addresses, ~32 hits each)
__global__ void deg_kernel(const int* __restrict__ ei, int* __restrict__ deg) {
    int i = blockIdx.x * 256 + threadIdx.x;       // groups of 4 edges
    if (i >= N_EDGES / 4) return;
    int4 d = ((const int4*)(ei + N_EDGES))[i];
    atomicAdd(&deg[d.x], 1);
    atomicAdd(&deg[d.y], 1);
    atomicAdd(&deg[d.z], 1);
    atomicAdd(&deg[d.w], 1);
}

__global__ void bsum_kernel(const int* __restrict__ deg, int* __restrict__ bcnt) {
    __shared__ int wsum[2];
    int b = blockIdx.x, t = threadIdx.x;
    int n = b * 128 + t;
    int v = (n < N_NODES) ? deg[n] : 0;
#pragma unroll
    for (int off = 1; off < 64; off <<= 1) v += __shfl_xor(v, off);
    if ((t & 63) == 0) wsum[t >> 6] = v;
    __syncthreads();
    if (t == 0) bcnt[b] = wsum[0] + wsum[1];
}

__global__ void scan391_kernel(const int* __restrict__ bcnt, int* __restrict__ bbase) {
    __shared__ int wtot[8];
    int b = threadIdx.x;              // 512 threads, 8 waves
    int lane = b & 63, w = b >> 6;
    int v = (b < NB) ? bcnt[b] : 0;
    int sc = v;
#pragma unroll
    for (int off = 1; off < 64; off <<= 1) {
        int u = __shfl_up(sc, off);
        if (lane >= off) sc += u;
    }
    if (lane == 63) wtot[w] = sc;
    __syncthreads();
    int add = 0;
    for (int k = 0; k < w; ++k) add += wtot[k];
    int excl = sc - v + add;
    if (b < NB) bbase[b] = excl;
    if (b == 0) bbase[NB] = N_EDGES;
}

// per-bucket scan of deg -> rowptr + global cursor copy
__global__ void rowptr_kernel(const int* __restrict__ deg, const int* __restrict__ bbase,
                              int* __restrict__ rowptr, int* __restrict__ cur) {
    __shared__ int wt[2];
    const int b = blockIdx.x;
    const int n0 = b * 128;
    const int t = threadIdx.x;        // 128 threads
    const int base = bbase[b];
    int n = n0 + t;
    int v = (n < N_NODES) ? deg[n] : 0;
    int lane = t & 63, w = t >> 6;
    int sc = v;
#pragma unroll
    for (int off = 1; off < 64; off <<= 1) {
        int u = __shfl_up(sc, off);
        if (lane >= off) sc += u;
    }
    if (lane == 63) wt[w] = sc;
    __syncthreads();
    int add = (t >= 64) ? wt[0] : 0;
    int excl = sc - v + add;
    if (n <= N_NODES) rowptr[n] = base + excl;   // rowptr[N] emitted by last bucket
    if (n < N_NODES) cur[n] = base + excl;
}

// direct placement: atomics over 50k cursors; csr (3.2MB) is XCD-L2-resident
__global__ void scatter_kernel(const int* __restrict__ ei, int* __restrict__ cur,
                               unsigned short* __restrict__ csr) {
    int i = blockIdx.x * 256 + threadIdx.x;       // groups of 4 edges
    if (i >= N_EDGES / 4) return;
    int4 s = ((const int4*)ei)[i];
    int4 d = ((const int4*)(ei + N_EDGES))[i];
    int p0 = atomicAdd(&cur[d.x], 1); csr[p0] = (unsigned short)s.x;
    int p1 = atomicAdd(&cur[d.y], 1); csr[p1] = (unsigned short)s.y;
    int p2 = atomicAdd(&cur[d.z], 1); csr[p2] = (unsigned short)s.z;
    int p3 = atomicAdd(&cur[d.w], 1); csr[p3] = (unsigned short)s.w;
}

// ------- agg layers 1/2 (HC=64): dual-edge half-wave gather -------
__global__ void agg64_kernel(const int* __restrict__ rowptr, const unsigned short* __restrict__ csr_src,
                             const float* __restrict__ al_s, const float* __restrict__ al_d,
                             const unsigned short* __restrict__ hb, const float* __restrict__ b,
                             float* __restrict__ xn) {
    int node = blockIdx.x * 4 + (threadIdx.x >> 6);   // grid exact: N_NODES % 4 == 0
    int lane = threadIdx.x & 63;
    int half = lane >> 5;
    int hl = lane & 31;
    int c0 = hl * 2;
    int hd = hl >> 3;                                 // head = (2*hl)/16
    float ald = al_d[node * 4 + hd];
    int beg = rowptr[node], end = rowptr[node + 1];
    float denom = 0.f, a0 = 0.f, a1 = 0.f;
    if (half == 0) {   // self loop on half 0
        float w = __expf(lrelu02(al_s[node * 4 + hd] + ald));
        float2 p = bfp2(*(const unsigned int*)(hb + (size_t)node * 64 + c0));
        denom = w; a0 = w * p.x; a1 = w * p.y;
    }
    int j = beg + half;
    for (; j + 6 < end; j += 8) {   // 4 edges per half = 8 edges per wave
        int s0 = csr_src[j], s1 = csr_src[j + 2], s2 = csr_src[j + 4], s3 = csr_src[j + 6];
        unsigned int q0 = *(const unsigned int*)(hb + (size_t)s0 * 64 + c0);
        unsigned int q1 = *(const unsigned int*)(hb + (size_t)s1 * 64 + c0);
        unsigned int q2 = *(const unsigned int*)(hb + (size_t)s2 * 64 + c0);
        unsigned int q3 = *(const unsigned int*)(hb + (size_t)s3 * 64 + c0);
        float w0 = __expf(lrelu02(al_s[s0 * 4 + hd] + ald));
        float w1 = __expf(lrelu02(al_s[s1 * 4 + hd] + ald));
        float w2 = __expf(lrelu02(al_s[s2 * 4 + hd] + ald));
        float w3 = __expf(lrelu02(al_s[s3 * 4 + hd] + ald));
        denom += (w0 + w1) + (w2 + w3);
        float2 p;
        p = bfp2(q0); a0 = fmaf(w0, p.x, a0); a1 = fmaf(w0, p.y, a1);
        p = bfp2(q1); a0 = fmaf(w1, p.x, a0); a1 = fmaf(w1, p.y, a1);
        p = bfp2(q2); a0 = fmaf(w2, p.x, a0); a1 = fmaf(w2, p.y, a1);
        p = bfp2(q3); a0 = fmaf(w3, p.x, a0); a1 = fmaf(w3, p.y, a1);
    }
    for (; j < end; j += 2) {
        int s0 = csr_src[j];
        unsigned int q0 = *(const unsigned int*)(hb + (size_t)s0 * 64 + c0);
        float w0 = __expf(lrelu02(al_s[s0 * 4 + hd] + ald));
        denom += w0;
        float2 p = bfp2(q0);
        a0 = fmaf(w0, p.x, a0); a1 = fmaf(w0, p.y, a1);
    }
    denom += __shfl_xor(denom, 32);
    a0 += __shfl_xor(a0, 32);
    a1 += __shfl_xor(a1, 32);
    if (half == 0) {
        float2 o;
        o.x = elu1(a0 / denom + b[c0]);
        o.y = elu1(a1 / denom + b[c0 + 1]);
        *(float2*)(xn + (size_t)node * 64 + c0) = o;
    }
}

// ------- agg layer 3: fp8 gather (uint/lane = 4 ch, 64 lanes = full 256B row); fused final -------
__global__ void agg240_kernel(const int* __restrict__ rowptr, const unsigned short* __restrict__ csr_src,
                              const float* __restrict__ al_s, const float* __restrict__ al_d,
                              const unsigned int* __restrict__ h8, const float* __restrict__ b3,
                              float* __restrict__ y) {
    __shared__ float sh[4][240];
    int wv_id = threadIdx.x >> 6;
    int node = blockIdx.x * 4 + wv_id;                // grid exact: 12500 blocks
    int lane = threadIdx.x & 63;
    bool act = lane < 60;
    int c0 = lane * 4;                                // 0..252 (pad region for lanes 60-63)
    int hd = act ? (c0 / 40) : 5;                     // clamp for pad lanes
    float ald = al_d[node * 6 + hd];
    int beg = rowptr[node], end = rowptr[node + 1];
    float w = __expf(lrelu02(al_s[node * 6 + hd] + ald));
    float denom = w;
    float4 acc;
    {
        unsigned int q = h8[(size_t)node * 64 + lane];
        v2f lo = __builtin_amdgcn_cvt_pk_f32_fp8((int)q, false);
        v2f hi = __builtin_amdgcn_cvt_pk_f32_fp8((int)q, true);
        acc.x = w * lo.x; acc.y = w * lo.y; acc.z = w * hi.x; acc.w = w * hi.y;
    }
    int j = beg;
    for (; j + 8 <= end; j += 8) {
        int s[8];
#pragma unroll
        for (int u = 0; u < 8; ++u) s[u] = csr_src[j + u];
        unsigned int q[8];
#pragma unroll
        for (int u = 0; u < 8; ++u) q[u] = h8[(size_t)s[u] * 64 + lane];
        float wvv[8];
#pragma unroll
        for (int u = 0; u < 8; ++u) wvv[u] = __expf(lrelu02(al_s[s[u] * 6 + hd] + ald));
#pragma unroll
        for (int u = 0; u < 8; ++u) {
            denom += wvv[u];
            v2f lo = __builtin_amdgcn_cvt_pk_f32_fp8((int)q[u], false);
            v2f hi = __builtin_amdgcn_cvt_pk_f32_fp8((int)q[u], true);
            acc.x = fmaf(wvv[u], lo.x, acc.x); acc.y = fmaf(wvv[u], lo.y, acc.y);
            acc.z = fmaf(wvv[u], hi.x, acc.z); acc.w = fmaf(wvv[u], hi.y, acc.w);
        }
    }
    for (; j < end; ++j) {
        int s0 = csr_src[j];
        unsigned int q0 = h8[(size_t)s0 * 64 + lane];
        float w0 = __expf(lrelu02(al_s[s0 * 6 + hd] + ald));
        denom += w0;
        v2f lo = __builtin_amdgcn_cvt_pk_f32_fp8((int)q0, false);
        v2f hi = __builtin_amdgcn_cvt_pk_f32_fp8((int)q0, true);
        acc.x = fmaf(w0, lo.x, acc.x); acc.y = fmaf(w0, lo.y, acc.y);
        acc.z = fmaf(w0, hi.x, acc.z); acc.w = fmaf(w0, hi.y, acc.w);
    }
    if (act) {
        float r = 1.f / denom;
        float* sp = &sh[wv_id][c0];
        sp[0] = acc.x * r; sp[1] = acc.y * r; sp[2] = acc.z * r; sp[3] = acc.w * r;
    }
    __syncthreads();
    float v;
    if (lane < 40) {
        const float* p = sh[wv_id];
        float s = 0.f;
#pragma unroll
        for (int hh = 0; hh < 6; ++hh) s += p[hh * 40 + lane];
        v = elu1(s * (1.f / 6.f) + b3[lane]);
    } else {
        v = -INFINITY;
    }
    float m = v;
#pragma unroll
    for (int o = 32; o > 0; o >>= 1) m = fmaxf(m, __shfl_xor(m, o));
    float ex = (lane < 40) ? __expf(v - m) : 0.f;
    float ssum = ex;
#pragma unroll
    for (int o = 32; o > 0; o >>= 1) ssum += __shfl_xor(ssum, o);
    if (lane < 40) y[(size_t)node * 40 + lane] = v - m - __logf(ssum);
}

extern "C" void kernel_launch(void* const* d_in, const int* in_sizes, int n_in,
                              void* d_out, int out_size, void* d_ws, size_t ws_size,
                              hipStream_t stream) {
    const float* x   = (const float*)d_in[0];
    const int*   ei  = (const int*)d_in[1];   // [2, E]
    const float* W1  = (const float*)d_in[2];
    const float* a1s = (const float*)d_in[3];
    const float* a1d = (const float*)d_in[4];
    const float* b1  = (const float*)d_in[5];
    const float* W2  = (const float*)d_in[6];
    const float* a2s = (const float*)d_in[7];
    const float* a2d = (const float*)d_in[8];
    const float* b2  = (const float*)d_in[9];
    const float* W3  = (const float*)d_in[10];
    const float* a3s = (const float*)d_in[11];
    const float* a3d = (const float*)d_in[12];
    const float* b3  = (const float*)d_in[13];
    float* y = (float*)d_out;

    float* ws = (float*)d_ws;
    unsigned short* h_bf = (unsigned short*)ws;               // 3.2M ushort (layers 1/2)
    float* x_buf   = ws + 1600000;                            // 3,200,000 floats
    float* al_s    = ws + 4800000;                            //   300,000
    float* al_d    = ws + 5100000;                            //   300,000
    unsigned int* h8 = (unsigned int*)(ws + 5400000);         // 3.2M uints (layer-3 fp8, 256B rows)
    int*   deg     = (int*)(ws + 8600000);                    //    50,000
    int*   rowptr  = (int*)(ws + 8650000);                    //    50,001
    unsigned short* csr_src = (unsigned short*)(ws + 8700008);  // 1.6M ushort
    int*   cur     = (int*)(ws + 9500008);                    //    50,000 (placement cursors)
    int*   bcnt    = (int*)(ws + 9550008);                    //    NB ints
    int*   bbase   = (int*)(ws + 9550400);                    //    NB+1 ints

    // ---- CSR build v2: histogram -> hierarchical scan -> direct atomic placement ----
    hipMemsetAsync(deg, 0, N_NODES * sizeof(int), stream);
    deg_kernel<<<(N_EDGES / 4 + 255) / 256, 256, 0, stream>>>(ei, deg);
    bsum_kernel<<<NB, 128, 0, stream>>>(deg, bcnt);
    scan391_kernel<<<1, 512, 0, stream>>>(bcnt, bbase);
    rowptr_kernel<<<NB, 128, 0, stream>>>(deg, bbase, rowptr, cur);
    scatter_kernel<<<(N_EDGES / 4 + 255) / 256, 256, 0, stream>>>(ei, cur, csr_src);

    const int agg_grid = N_NODES / 4;              // 12500, exact
    const int gemm_gx = (N_NODES + 63) / 64;       // 782 blocks of 64 rows

    // ---- layer 1: 128 -> (4,16) concat ----
    gemm_al_kernel<128><<<gemm_gx, 256, 0, stream>>>(x, W1, a1s, a1d, h_bf, al_s, al_d);
    agg64_kernel<<<agg_grid, 256, 0, stream>>>(rowptr, csr_src, al_s, al_d, h_bf, b1, x_buf);

    // ---- layer 2: 64 -> (4,16) concat ----
    gemm_al_kernel<64><<<gemm_gx, 256, 0, stream>>>(x_buf, W2, a2s, a2d, h_bf, al_s, al_d);
    agg64_kernel<<<agg_grid, 256, 0, stream>>>(rowptr, csr_src, al_s, al_d, h_bf, b2, x_buf);

    // ---- layer 3: 64 -> (6,40) mean; fp8 h; 3 col-blocks of 80 ----
    gemm80_kernel<<<gemm_gx * 3, 256, 0, stream>>>(x_buf, W3, a3s, a3d, h8, al_s, al_d);
    agg240_kernel<<<agg_grid, 256, 0, stream>>>(rowptr, csr_src, al_s, al_d, h8, b3, y);
}

// Round 3
// 364.870 us; speedup vs baseline: 1.3630x; 1.3630x over previous
//
#include <hip/hip_runtime.h>
#include <math.h>

#define N_NODES 50000
#define N_EDGES 1600000
#define NB      391          // ceil(50000/128) buckets of 128 nodes
#define CHUNK   8192         // edges per multisplit block
#define NCHUNK  196          // ceil(1600000/8192)

typedef __attribute__((ext_vector_type(2))) float v2f;
typedef __attribute__((ext_vector_type(4))) float f32x4;
typedef __attribute__((ext_vector_type(8))) __bf16 bf16x8;

__device__ __forceinline__ float lrelu02(float x) { return x > 0.f ? x : 0.2f * x; }
__device__ __forceinline__ float elu1(float x)    { return x > 0.f ? x : __expf(x) - 1.f; }

// bf16 helpers (RNE pack)
__device__ __forceinline__ unsigned short f2bf(float f) {
    unsigned int u = __float_as_uint(f);
    return (unsigned short)((u + 0x7fffu + ((u >> 16) & 1u)) >> 16);
}
__device__ __forceinline__ float bf2f(unsigned short s) {
    return __uint_as_float((unsigned int)s << 16);
}
__device__ __forceinline__ float2 bfp2(unsigned int u) {
    float2 r;
    r.x = __uint_as_float(u << 16);
    r.y = __uint_as_float(u & 0xffff0000u);
    return r;
}

union BF8U { unsigned short u[8]; bf16x8 v; };
__device__ __forceinline__ bf16x8 cvt8(float4 a, float4 b) {
    BF8U r;
    r.u[0] = f2bf(a.x); r.u[1] = f2bf(a.y); r.u[2] = f2bf(a.z); r.u[3] = f2bf(a.w);
    r.u[4] = f2bf(b.x); r.u[5] = f2bf(b.y); r.u[6] = f2bf(b.z); r.u[7] = f2bf(b.w);
    return r.v;
}

// ------- GEMM layers 1/2 (FOUT=64) via MFMA bf16, fused attention logits -------
template<int FIN>
__global__ __launch_bounds__(256) void gemm_al_kernel(const float* __restrict__ x,
                               const float* __restrict__ W,
                               const float* __restrict__ a_s, const float* __restrict__ a_d,
                               unsigned short* __restrict__ h,
                               float* __restrict__ al_s, float* __restrict__ al_d) {
    constexpr int KS = FIN / 32;
    __shared__ alignas(16) unsigned short Wl[KS * 64 * 32];   // bf16, FIN*64*2 B
    __shared__ alignas(16) unsigned short ot[64][64];         // block output, bf16
    const int tid = threadIdx.x;
    for (int i = tid; i < FIN * 64; i += 256) {
        int ks = i >> 11;            // / (64*32)
        int rem = i & 2047;
        int c = rem >> 5, r = rem & 31;
        Wl[i] = f2bf(W[(ks * 32 + r) * 64 + c]);
    }
    __syncthreads();

    const int wv = tid >> 6, l = tid & 63;
    const int m = l & 15, g = l >> 4;
    const int n0 = blockIdx.x * 64;
    int row = n0 + wv * 16 + m;
    if (row > N_NODES - 1) row = N_NODES - 1;     // tail clamp; results discarded
    const float* xr = x + (size_t)row * FIN + g * 8;

    f32x4 acc[4] = {};   // 4 col-tiles of 16
#pragma unroll
    for (int ks = 0; ks < KS; ++ks) {
        float4 xa = *(const float4*)(xr + ks * 32);
        float4 xb = *(const float4*)(xr + ks * 32 + 4);
        bf16x8 af = cvt8(xa, xb);
        const unsigned short* wp = &Wl[ks * 2048 + g * 8];
#pragma unroll
        for (int t = 0; t < 4; ++t) {
            bf16x8 bf = *(const bf16x8*)(wp + (t * 16 + m) * 32);
            acc[t] = __builtin_amdgcn_mfma_f32_16x16x32_bf16(af, bf, acc[t], 0, 0, 0);
        }
    }
    // C/D layout: col = lane&15, row = (lane>>4)*4 + reg  [HW-verified]
#pragma unroll
    for (int t = 0; t < 4; ++t)
#pragma unroll
        for (int j = 0; j < 4; ++j)
            ot[wv * 16 + g * 4 + j][t * 16 + m] = f2bf(acc[t][j]);
    __syncthreads();

    int vrows = N_NODES - n0; if (vrows > 64) vrows = 64;
    {   // node-major coalesced h writeout (bf16 pairs as uints)
        unsigned int* ph = (unsigned int*)(h + (size_t)n0 * 64);
        for (int i = tid; i < vrows * 32; i += 256) {
            int r = i >> 5, c = i & 31;
            ph[i] = *(const unsigned int*)&ot[r][c * 2];
        }
    }
    // fused al_s / al_d: 64 nodes x 4 heads = 256 threads
    {
        int node = tid >> 2, hd = tid & 3;
        if (node < vrows) {
            const float* as = a_s + hd * 16;
            const float* ad = a_d + hd * 16;
            float s1 = 0.f, s2 = 0.f;
#pragma unroll
            for (int c = 0; c < 16; c += 2) {
                unsigned int q = *(const unsigned int*)&ot[node][hd * 16 + c];
                float2 p = bfp2(q);
                s1 = fmaf(p.x, as[c], s1);     s2 = fmaf(p.x, ad[c], s2);
                s1 = fmaf(p.y, as[c + 1], s1); s2 = fmaf(p.y, ad[c + 1], s2);
            }
            al_s[(n0 + node) * 4 + hd] = s1;
            al_d[(n0 + node) * 4 + hd] = s2;
        }
    }
}

// ------- L3 GEMM via MFMA: N=240 split into 3 col-blocks of 80 (5 tiles, 2 heads each) -------
__global__ __launch_bounds__(256) void gemm80_kernel(const float* __restrict__ x,
                              const float* __restrict__ W,
                              const float* __restrict__ a_s, const float* __restrict__ a_d,
                              unsigned int* __restrict__ h8,
                              float* __restrict__ al_s, float* __restrict__ al_d) {
    __shared__ alignas(16) unsigned short Wl[2 * 80 * 32];    // 10 KB
    __shared__ alignas(16) unsigned short ot[64][80];         // 10 KB
    const int tid = threadIdx.x;
    const int nb = blockIdx.x / 3, third = blockIdx.x % 3;
    const int cb = third * 80;
    for (int i = tid; i < 2 * 80 * 32; i += 256) {
        int ks = i / 2560;
        int rem = i - ks * 2560;
        int c = rem >> 5, r = rem & 31;
        Wl[i] = f2bf(W[(ks * 32 + r) * 240 + cb + c]);
    }
    __syncthreads();

    const int wv = tid >> 6, l = tid & 63;
    const int m = l & 15, g = l >> 4;
    const int n0 = nb * 64;
    int row = n0 + wv * 16 + m;
    if (row > N_NODES - 1) row = N_NODES - 1;
    const float* xr = x + (size_t)row * 64 + g * 8;

    f32x4 acc[5] = {};
#pragma unroll
    for (int ks = 0; ks < 2; ++ks) {
        float4 xa = *(const float4*)(xr + ks * 32);
        float4 xb = *(const float4*)(xr + ks * 32 + 4);
        bf16x8 af = cvt8(xa, xb);
        const unsigned short* wp = &Wl[ks * 2560 + g * 8];
#pragma unroll
        for (int t = 0; t < 5; ++t) {
            bf16x8 bf = *(const bf16x8*)(wp + (t * 16 + m) * 32);
            acc[t] = __builtin_amdgcn_mfma_f32_16x16x32_bf16(af, bf, acc[t], 0, 0, 0);
        }
    }
#pragma unroll
    for (int t = 0; t < 5; ++t)
#pragma unroll
        for (int j = 0; j < 4; ++j)
            ot[wv * 16 + g * 4 + j][t * 16 + m] = f2bf(acc[t][j]);
    __syncthreads();

    int vrows = N_NODES - n0; if (vrows > 64) vrows = 64;
    {   // fp8 writeout: this col-third owns 20 uints of each 64-uint row
        for (int i = tid; i < vrows * 20; i += 256) {
            int r = i / 20, c = i - r * 20;
            uint2 q = *(const uint2*)&ot[r][c * 4];
            float2 p0 = bfp2(q.x), p1 = bfp2(q.y);
            int lo = __builtin_amdgcn_cvt_pk_fp8_f32(p0.x, p0.y, 0, false);
            unsigned int packed = (unsigned int)__builtin_amdgcn_cvt_pk_fp8_f32(p1.x, p1.y, lo, true);
            h8[(size_t)(n0 + r) * 64 + cb / 4 + c] = packed;
        }
        if (third == 0) {  // zero the 4 pad uints per row
            for (int i = tid; i < vrows * 4; i += 256)
                h8[(size_t)(n0 + (i >> 2)) * 64 + 60 + (i & 3)] = 0;
        }
    }
    // al3 for the 2 heads of this col-third: 64 nodes x 2 heads = 128 threads
    for (int t = tid; t < vrows * 2; t += 256) {
        int node = t >> 1, hh = t & 1;
        int hd = third * 2 + hh;
        const unsigned short* rp = &ot[node][hh * 40];
        const float* as = a_s + hd * 40;
        const float* ad = a_d + hd * 40;
        float s1 = 0.f, s2 = 0.f;
#pragma unroll
        for (int c = 0; c < 40; c += 2) {
            unsigned int q = *(const unsigned int*)(rp + c);
            float2 p = bfp2(q);
            s1 = fmaf(p.x, as[c], s1);     s2 = fmaf(p.x, ad[c], s2);
            s1 = fmaf(p.y, as[c + 1], s1); s2 = fmaf(p.y, ad[c + 1], s2);
        }
        al_s[(n0 + node) * 6 + hd] = s1;
        al_d[(n0 + node) * 6 + hd] = s2;
    }
}

// ---------------- CSR build v3: LDS multisplit, block-private scattered writes ----------------
// Pass A: per-block LDS histogram of bucket counts; one global atomic per (block,bucket)
__global__ __launch_bounds__(256) void bcnt_kernel(const int* __restrict__ ei, int* __restrict__ bcnt) {
    __shared__ int hist[NB];
    const int t = threadIdx.x;
    for (int i = t; i < NB; i += 256) hist[i] = 0;
    __syncthreads();
    const int e0 = blockIdx.x * CHUNK;
    int n = N_EDGES - e0; if (n > CHUNK) n = CHUNK;     // n % 4 == 0 always
    const int4* d4 = (const int4*)(ei + N_EDGES) + (e0 >> 2);
    for (int i = t; i < (n >> 2); i += 256) {
        int4 d = d4[i];
        atomicAdd(&hist[d.x >> 7], 1);
        atomicAdd(&hist[d.y >> 7], 1);
        atomicAdd(&hist[d.z >> 7], 1);
        atomicAdd(&hist[d.w >> 7], 1);
    }
    __syncthreads();
    for (int b = t; b < NB; b += 256)
        if (hist[b]) atomicAdd(&bcnt[b], hist[b]);
}

__global__ void scan391_kernel(const int* __restrict__ bcnt, int* __restrict__ bbase,
                               int* __restrict__ bcur) {
    __shared__ int wtot[8];
    int b = threadIdx.x;              // 512 threads, 8 waves
    int lane = b & 63, w = b >> 6;
    int v = (b < NB) ? bcnt[b] : 0;
    int sc = v;
#pragma unroll
    for (int off = 1; off < 64; off <<= 1) {
        int u = __shfl_up(sc, off);
        if (lane >= off) sc += u;
    }
    if (lane == 63) wtot[w] = sc;
    __syncthreads();
    int add = 0;
    for (int k = 0; k < w; ++k) add += wtot[k];
    int excl = sc - v + add;
    if (b < NB) { bbase[b] = excl; bcur[b * 16] = excl; }
    if (b == 0) bbase[NB] = N_EDGES;
}

// Pass B: multisplit — LDS-staged chunk, per-bucket run reservation, ranked run writes.
// Each 64B stage line is filled by (mostly) one block -> no cross-XCD line thrash.
__global__ __launch_bounds__(256) void bucket2_kernel(const int* __restrict__ ei,
                                                      int* __restrict__ bcur,
                                                      unsigned int* __restrict__ stage) {
    __shared__ unsigned int vals[CHUNK];   // 32 KB: (dst<<16)|src
    __shared__ int hist[NB];
    __shared__ int cnt2[NB];
    __shared__ int gbase[NB];
    const int t = threadIdx.x;
    for (int i = t; i < NB; i += 256) { hist[i] = 0; cnt2[i] = 0; }
    __syncthreads();
    const int e0 = blockIdx.x * CHUNK;
    int n = N_EDGES - e0; if (n > CHUNK) n = CHUNK;     // n % 4 == 0
    const int4* s4 = (const int4*)ei + (e0 >> 2);
    const int4* d4 = (const int4*)(ei + N_EDGES) + (e0 >> 2);
    for (int i = t; i < (n >> 2); i += 256) {
        int4 s = s4[i], d = d4[i];
        vals[4 * i + 0] = ((unsigned int)d.x << 16) | (unsigned int)s.x;
        vals[4 * i + 1] = ((unsigned int)d.y << 16) | (unsigned int)s.y;
        vals[4 * i + 2] = ((unsigned int)d.z << 16) | (unsigned int)s.z;
        vals[4 * i + 3] = ((unsigned int)d.w << 16) | (unsigned int)s.w;
        atomicAdd(&hist[d.x >> 7], 1);
        atomicAdd(&hist[d.y >> 7], 1);
        atomicAdd(&hist[d.z >> 7], 1);
        atomicAdd(&hist[d.w >> 7], 1);
    }
    __syncthreads();
    for (int b = t; b < NB; b += 256)
        if (hist[b]) gbase[b] = atomicAdd(&bcur[b * 16], hist[b]);
    __syncthreads();
    for (int i = t; i < n; i += 256) {
        unsigned int v = vals[i];
        int b = v >> 23;                                  // dst>>7
        int r = atomicAdd(&cnt2[b], 1);
        stage[gbase[b] + r] = v & 0x7FFFFFu;              // ((dst&127)<<16)|src
    }
}

// Pass C: per-bucket placement. Degrees computed from own stage region; all
// scattered csr writes land in this block's private [bbase[b], bbase[b+1]) region.
__global__ __launch_bounds__(256) void place2_kernel(const unsigned int* __restrict__ stage,
                                                     const int* __restrict__ bbase,
                                                     int* __restrict__ rowptr,
                                                     unsigned short* __restrict__ csr) {
    __shared__ int hist[128];
    __shared__ int cur[128];
    __shared__ int wt[2];
    const int b = blockIdx.x;
    const int n0 = b * 128;
    const int t = threadIdx.x;
    const int base = bbase[b];
    const int endp = bbase[b + 1];
    if (t < 128) hist[t] = 0;
    __syncthreads();
    for (int i = base + t; i < endp; i += 256)
        atomicAdd(&hist[stage[i] >> 16], 1);
    __syncthreads();
    int v = 0, sc = 0;
    if (t < 128) {
        v = hist[t];
        int lane = t & 63, w = t >> 6;
        sc = v;
#pragma unroll
        for (int off = 1; off < 64; off <<= 1) {
            int u = __shfl_up(sc, off);
            if (lane >= off) sc += u;
        }
        if (lane == 63) wt[w] = sc;
    }
    __syncthreads();
    if (t < 128) {
        int add = (t >= 64) ? wt[0] : 0;
        int excl = sc - v + add;
        int n = n0 + t;
        if (n <= N_NODES) rowptr[n] = base + excl;   // rowptr[N] emitted by last bucket
        cur[t] = base + excl;
    }
    __syncthreads();
    for (int i = base + t; i < endp; i += 256) {
        unsigned int e = stage[i];
        int pos = atomicAdd(&cur[e >> 16], 1);
        csr[pos] = (unsigned short)(e & 0xFFFFu);
    }
}

// ------- agg layers 1/2 (HC=64): dual-edge half-wave gather -------
__global__ void agg64_kernel(const int* __restrict__ rowptr, const unsigned short* __restrict__ csr_src,
                             const float* __restrict__ al_s, const float* __restrict__ al_d,
                             const unsigned short* __restrict__ hb, const float* __restrict__ b,
                             float* __restrict__ xn) {
    int node = blockIdx.x * 4 + (threadIdx.x >> 6);   // grid exact: N_NODES % 4 == 0
    int lane = threadIdx.x & 63;
    int half = lane >> 5;
    int hl = lane & 31;
    int c0 = hl * 2;
    int hd = hl >> 3;                                 // head = (2*hl)/16
    float ald = al_d[node * 4 + hd];
    int beg = rowptr[node], end = rowptr[node + 1];
    float denom = 0.f, a0 = 0.f, a1 = 0.f;
    if (half == 0) {   // self loop on half 0
        float w = __expf(lrelu02(al_s[node * 4 + hd] + ald));
        float2 p = bfp2(*(const unsigned int*)(hb + (size_t)node * 64 + c0));
        denom = w; a0 = w * p.x; a1 = w * p.y;
    }
    int j = beg + half;
    for (; j + 6 < end; j += 8) {   // 4 edges per half = 8 edges per wave
        int s0 = csr_src[j], s1 = csr_src[j + 2], s2 = csr_src[j + 4], s3 = csr_src[j + 6];
        unsigned int q0 = *(const unsigned int*)(hb + (size_t)s0 * 64 + c0);
        unsigned int q1 = *(const unsigned int*)(hb + (size_t)s1 * 64 + c0);
        unsigned int q2 = *(const unsigned int*)(hb + (size_t)s2 * 64 + c0);
        unsigned int q3 = *(const unsigned int*)(hb + (size_t)s3 * 64 + c0);
        float w0 = __expf(lrelu02(al_s[s0 * 4 + hd] + ald));
        float w1 = __expf(lrelu02(al_s[s1 * 4 + hd] + ald));
        float w2 = __expf(lrelu02(al_s[s2 * 4 + hd] + ald));
        float w3 = __expf(lrelu02(al_s[s3 * 4 + hd] + ald));
        denom += (w0 + w1) + (w2 + w3);
        float2 p;
        p = bfp2(q0); a0 = fmaf(w0, p.x, a0); a1 = fmaf(w0, p.y, a1);
        p = bfp2(q1); a0 = fmaf(w1, p.x, a0); a1 = fmaf(w1, p.y, a1);
        p = bfp2(q2); a0 = fmaf(w2, p.x, a0); a1 = fmaf(w2, p.y, a1);
        p = bfp2(q3); a0 = fmaf(w3, p.x, a0); a1 = fmaf(w3, p.y, a1);
    }
    for (; j < end; j += 2) {
        int s0 = csr_src[j];
        unsigned int q0 = *(const unsigned int*)(hb + (size_t)s0 * 64 + c0);
        float w0 = __expf(lrelu02(al_s[s0 * 4 + hd] + ald));
        denom += w0;
        float2 p = bfp2(q0);
        a0 = fmaf(w0, p.x, a0); a1 = fmaf(w0, p.y, a1);
    }
    denom += __shfl_xor(denom, 32);
    a0 += __shfl_xor(a0, 32);
    a1 += __shfl_xor(a1, 32);
    if (half == 0) {
        float2 o;
        o.x = elu1(a0 / denom + b[c0]);
        o.y = elu1(a1 / denom + b[c0 + 1]);
        *(float2*)(xn + (size_t)node * 64 + c0) = o;
    }
}

// ------- agg layer 3: fp8 gather (uint/lane = 4 ch, 64 lanes = full 256B row); fused final -------
__global__ void agg240_kernel(const int* __restrict__ rowptr, const unsigned short* __restrict__ csr_src,
                              const float* __restrict__ al_s, const float* __restrict__ al_d,
                              const unsigned int* __restrict__ h8, const float* __restrict__ b3,
                              float* __restrict__ y) {
    __shared__ float sh[4][240];
    int wv_id = threadIdx.x >> 6;
    int node = blockIdx.x * 4 + wv_id;                // grid exact: 12500 blocks
    int lane = threadIdx.x & 63;
    bool act = lane < 60;
    int c0 = lane * 4;                                // 0..252 (pad region for lanes 60-63)
    int hd = act ? (c0 / 40) : 5;                     // clamp for pad lanes
    float ald = al_d[node * 6 + hd];
    int beg = rowptr[node], end = rowptr[node + 1];
    float w = __expf(lrelu02(al_s[node * 6 + hd] + ald));
    float denom = w;
    float4 acc;
    {
        unsigned int q = h8[(size_t)node * 64 + lane];
        v2f lo = __builtin_amdgcn_cvt_pk_f32_fp8((int)q, false);
        v2f hi = __builtin_amdgcn_cvt_pk_f32_fp8((int)q, true);
        acc.x = w * lo.x; acc.y = w * lo.y; acc.z = w * hi.x; acc.w = w * hi.y;
    }
    int j = beg;
    for (; j + 8 <= end; j += 8) {
        int s[8];
#pragma unroll
        for (int u = 0; u < 8; ++u) s[u] = csr_src[j + u];
        unsigned int q[8];
#pragma unroll
        for (int u = 0; u < 8; ++u) q[u] = h8[(size_t)s[u] * 64 + lane];
        float wvv[8];
#pragma unroll
        for (int u = 0; u < 8; ++u) wvv[u] = __expf(lrelu02(al_s[s[u] * 6 + hd] + ald));
#pragma unroll
        for (int u = 0; u < 8; ++u) {
            denom += wvv[u];
            v2f lo = __builtin_amdgcn_cvt_pk_f32_fp8((int)q[u], false);
            v2f hi = __builtin_amdgcn_cvt_pk_f32_fp8((int)q[u], true);
            acc.x = fmaf(wvv[u], lo.x, acc.x); acc.y = fmaf(wvv[u], lo.y, acc.y);
            acc.z = fmaf(wvv[u], hi.x, acc.z); acc.w = fmaf(wvv[u], hi.y, acc.w);
        }
    }
    for (; j < end; ++j) {
        int s0 = csr_src[j];
        unsigned int q0 = h8[(size_t)s0 * 64 + lane];
        float w0 = __expf(lrelu02(al_s[s0 * 6 + hd] + ald));
        denom += w0;
        v2f lo = __builtin_amdgcn_cvt_pk_f32_fp8((int)q0, false);
        v2f hi = __builtin_amdgcn_cvt_pk_f32_fp8((int)q0, true);
        acc.x = fmaf(w0, lo.x, acc.x); acc.y = fmaf(w0, lo.y, acc.y);
        acc.z = fmaf(w0, hi.x, acc.z); acc.w = fmaf(w0, hi.y, acc.w);
    }
    if (act) {
        float r = 1.f / denom;
        float* sp = &sh[wv_id][c0];
        sp[0] = acc.x * r; sp[1] = acc.y * r; sp[2] = acc.z * r; sp[3] = acc.w * r;
    }
    __syncthreads();
    float v;
    if (lane < 40) {
        const float* p = sh[wv_id];
        float s = 0.f;
#pragma unroll
        for (int hh = 0; hh < 6; ++hh) s += p[hh * 40 + lane];
        v = elu1(s * (1.f / 6.f) + b3[lane]);
    } else {
        v = -INFINITY;
    }
    float m = v;
#pragma unroll
    for (int o = 32; o > 0; o >>= 1) m = fmaxf(m, __shfl_xor(m, o));
    float ex = (lane < 40) ? __expf(v - m) : 0.f;
    float ssum = ex;
#pragma unroll
    for (int o = 32; o > 0; o >>= 1) ssum += __shfl_xor(ssum, o);
    if (lane < 40) y[(size_t)node * 40 + lane] = v - m - __logf(ssum);
}

extern "C" void kernel_launch(void* const* d_in, const int* in_sizes, int n_in,
                              void* d_out, int out_size, void* d_ws, size_t ws_size,
                              hipStream_t stream) {
    const float* x   = (const float*)d_in[0];
    const int*   ei  = (const int*)d_in[1];   // [2, E]
    const float* W1  = (const float*)d_in[2];
    const float* a1s = (const float*)d_in[3];
    const float* a1d = (const float*)d_in[4];
    const float* b1  = (const float*)d_in[5];
    const float* W2  = (const float*)d_in[6];
    const float* a2s = (const float*)d_in[7];
    const float* a2d = (const float*)d_in[8];
    const float* b2  = (const float*)d_in[9];
    const float* W3  = (const float*)d_in[10];
    const float* a3s = (const float*)d_in[11];
    const float* a3d = (const float*)d_in[12];
    const float* b3  = (const float*)d_in[13];
    float* y = (float*)d_out;

    float* ws = (float*)d_ws;
    unsigned short* h_bf = (unsigned short*)ws;               // 3.2M ushort (layers 1/2)
    float* x_buf   = ws + 1600000;                            // 3,200,000 floats
    float* al_s    = ws + 4800000;                            //   300,000
    float* al_d    = ws + 5100000;                            //   300,000
    unsigned int* h8 = (unsigned int*)(ws + 5400000);         // 3.2M uints (layer-3 fp8, 256B rows)
    int*   rowptr  = (int*)(ws + 8600000);                    //    50,001
    unsigned short* csr_src = (unsigned short*)(ws + 8650008);  // 1.6M ushort
    unsigned int* stage = (unsigned int*)(ws + 9450008);      // 1.6M uint
    int*   bcnt    = (int*)(ws + 11050008);                   //    NB ints
    int*   bbase   = (int*)(ws + 11050400);                   //    NB+1 ints
    int*   bcur    = (int*)(ws + 11050792);                   //    NB*16 ints

    // ---- CSR build v3: LDS-hist -> scan -> multisplit -> private placement ----
    hipMemsetAsync(bcnt, 0, NB * sizeof(int), stream);
    bcnt_kernel<<<NCHUNK, 256, 0, stream>>>(ei, bcnt);
    scan391_kernel<<<1, 512, 0, stream>>>(bcnt, bbase, bcur);
    bucket2_kernel<<<NCHUNK, 256, 0, stream>>>(ei, bcur, stage);
    place2_kernel<<<NB, 256, 0, stream>>>(stage, bbase, rowptr, csr_src);

    const int agg_grid = N_NODES / 4;              // 12500, exact
    const int gemm_gx = (N_NODES + 63) / 64;       // 782 blocks of 64 rows

    // ---- layer 1: 128 -> (4,16) concat ----
    gemm_al_kernel<128><<<gemm_gx, 256, 0, stream>>>(x, W1, a1s, a1d, h_bf, al_s, al_d);
    agg64_kernel<<<agg_grid, 256, 0, stream>>>(rowptr, csr_src, al_s, al_d, h_bf, b1, x_buf);

    // ---- layer 2: 64 -> (4,16) concat ----
    gemm_al_kernel<64><<<gemm_gx, 256, 0, stream>>>(x_buf, W2, a2s, a2d, h_bf, al_s, al_d);
    agg64_kernel<<<agg_grid, 256, 0, stream>>>(rowptr, csr_src, al_s, al_d, h_bf, b2, x_buf);

    // ---- layer 3: 64 -> (6,40) mean; fp8 h; 3 col-blocks of 80 ----
    gemm80_kernel<<<gemm_gx * 3, 256, 0, stream>>>(x_buf, W3, a3s, a3d, h8, al_s, al_d);
    agg240_kernel<<<agg_grid, 256, 0, stream>>>(rowptr, csr_src, al_s, al_d, h8, b3, y);
}

// Round 4
// 346.821 us; speedup vs baseline: 1.4339x; 1.0520x over previous
//
#include <hip/hip_runtime.h>
#include <math.h>

#define N_NODES 50000
#define N_EDGES 1600000
#define NB      391          // ceil(50000/128) buckets of 128 nodes
#define CHUNK   8192         // edges per multisplit block
#define NCHUNK  196          // ceil(1600000/8192)
#define LOG2E   1.44269504088896340736f

typedef __attribute__((ext_vector_type(2))) float v2f;
typedef __attribute__((ext_vector_type(4))) float f32x4;
typedef __attribute__((ext_vector_type(8))) __bf16 bf16x8;

__device__ __forceinline__ float lrelu02(float x) { return fmaxf(x, 0.2f * x); }
__device__ __forceinline__ float elu1(float x)    { return x > 0.f ? x : __expf(x) - 1.f; }
// single v_exp_f32 (D = 2^S0); inputs are pre-scaled by log2e at al-store time
__device__ __forceinline__ float exp2_fast(float x) {
    float r; asm("v_exp_f32 %0, %1" : "=v"(r) : "v"(x)); return r;
}

// bf16 helpers (RNE pack)
__device__ __forceinline__ unsigned short f2bf(float f) {
    unsigned int u = __float_as_uint(f);
    return (unsigned short)((u + 0x7fffu + ((u >> 16) & 1u)) >> 16);
}
__device__ __forceinline__ float bf2f(unsigned short s) {
    return __uint_as_float((unsigned int)s << 16);
}
__device__ __forceinline__ float2 bfp2(unsigned int u) {
    float2 r;
    r.x = __uint_as_float(u << 16);
    r.y = __uint_as_float(u & 0xffff0000u);
    return r;
}

union BF8U { unsigned short u[8]; bf16x8 v; };
__device__ __forceinline__ bf16x8 cvt8(float4 a, float4 b) {
    BF8U r;
    r.u[0] = f2bf(a.x); r.u[1] = f2bf(a.y); r.u[2] = f2bf(a.z); r.u[3] = f2bf(a.w);
    r.u[4] = f2bf(b.x); r.u[5] = f2bf(b.y); r.u[6] = f2bf(b.z); r.u[7] = f2bf(b.w);
    return r.v;
}

// ------- GEMM layers 1/2 (FOUT=64) via MFMA bf16, fused attention logits -------
template<int FIN>
__global__ __launch_bounds__(256) void gemm_al_kernel(const float* __restrict__ x,
                               const float* __restrict__ W,
                               const float* __restrict__ a_s, const float* __restrict__ a_d,
                               unsigned short* __restrict__ h,
                               float* __restrict__ al_s, float* __restrict__ al_d) {
    constexpr int KS = FIN / 32;
    __shared__ alignas(16) unsigned short Wl[KS * 64 * 32];   // bf16, FIN*64*2 B
    __shared__ alignas(16) unsigned short ot[64][64];         // block output, bf16
    const int tid = threadIdx.x;
    for (int i = tid; i < FIN * 64; i += 256) {
        int ks = i >> 11;            // / (64*32)
        int rem = i & 2047;
        int c = rem >> 5, r = rem & 31;
        Wl[i] = f2bf(W[(ks * 32 + r) * 64 + c]);
    }
    __syncthreads();

    const int wv = tid >> 6, l = tid & 63;
    const int m = l & 15, g = l >> 4;
    const int n0 = blockIdx.x * 64;
    int row = n0 + wv * 16 + m;
    if (row > N_NODES - 1) row = N_NODES - 1;     // tail clamp; results discarded
    const float* xr = x + (size_t)row * FIN + g * 8;

    f32x4 acc[4] = {};   // 4 col-tiles of 16
#pragma unroll
    for (int ks = 0; ks < KS; ++ks) {
        float4 xa = *(const float4*)(xr + ks * 32);
        float4 xb = *(const float4*)(xr + ks * 32 + 4);
        bf16x8 af = cvt8(xa, xb);
        const unsigned short* wp = &Wl[ks * 2048 + g * 8];
#pragma unroll
        for (int t = 0; t < 4; ++t) {
            bf16x8 bf = *(const bf16x8*)(wp + (t * 16 + m) * 32);
            acc[t] = __builtin_amdgcn_mfma_f32_16x16x32_bf16(af, bf, acc[t], 0, 0, 0);
        }
    }
    // C/D layout: col = lane&15, row = (lane>>4)*4 + reg  [HW-verified]
#pragma unroll
    for (int t = 0; t < 4; ++t)
#pragma unroll
        for (int j = 0; j < 4; ++j)
            ot[wv * 16 + g * 4 + j][t * 16 + m] = f2bf(acc[t][j]);
    __syncthreads();

    int vrows = N_NODES - n0; if (vrows > 64) vrows = 64;
    {   // node-major coalesced h writeout (bf16 pairs as uints)
        unsigned int* ph = (unsigned int*)(h + (size_t)n0 * 64);
        for (int i = tid; i < vrows * 32; i += 256) {
            int r = i >> 5, c = i & 31;
            ph[i] = *(const unsigned int*)&ot[r][c * 2];
        }
    }
    // fused al_s / al_d: 64 nodes x 4 heads = 256 threads; stored pre-scaled by log2e
    {
        int node = tid >> 2, hd = tid & 3;
        if (node < vrows) {
            const float* as = a_s + hd * 16;
            const float* ad = a_d + hd * 16;
            float s1 = 0.f, s2 = 0.f;
#pragma unroll
            for (int c = 0; c < 16; c += 2) {
                unsigned int q = *(const unsigned int*)&ot[node][hd * 16 + c];
                float2 p = bfp2(q);
                s1 = fmaf(p.x, as[c], s1);     s2 = fmaf(p.x, ad[c], s2);
                s1 = fmaf(p.y, as[c + 1], s1); s2 = fmaf(p.y, ad[c + 1], s2);
            }
            al_s[(n0 + node) * 4 + hd] = s1 * LOG2E;
            al_d[(n0 + node) * 4 + hd] = s2 * LOG2E;
        }
    }
}

// ------- L3 GEMM via MFMA: N=240 split into 3 col-blocks of 80 (5 tiles, 2 heads each) -------
__global__ __launch_bounds__(256) void gemm80_kernel(const float* __restrict__ x,
                              const float* __restrict__ W,
                              const float* __restrict__ a_s, const float* __restrict__ a_d,
                              unsigned int* __restrict__ h8,
                              float* __restrict__ al_s, float* __restrict__ al_d) {
    __shared__ alignas(16) unsigned short Wl[2 * 80 * 32];    // 10 KB
    __shared__ alignas(16) unsigned short ot[64][80];         // 10 KB
    const int tid = threadIdx.x;
    const int nb = blockIdx.x / 3, third = blockIdx.x % 3;
    const int cb = third * 80;
    for (int i = tid; i < 2 * 80 * 32; i += 256) {
        int ks = i / 2560;
        int rem = i - ks * 2560;
        int c = rem >> 5, r = rem & 31;
        Wl[i] = f2bf(W[(ks * 32 + r) * 240 + cb + c]);
    }
    __syncthreads();

    const int wv = tid >> 6, l = tid & 63;
    const int m = l & 15, g = l >> 4;
    const int n0 = nb * 64;
    int row = n0 + wv * 16 + m;
    if (row > N_NODES - 1) row = N_NODES - 1;
    const float* xr = x + (size_t)row * 64 + g * 8;

    f32x4 acc[5] = {};
#pragma unroll
    for (int ks = 0; ks < 2; ++ks) {
        float4 xa = *(const float4*)(xr + ks * 32);
        float4 xb = *(const float4*)(xr + ks * 32 + 4);
        bf16x8 af = cvt8(xa, xb);
        const unsigned short* wp = &Wl[ks * 2560 + g * 8];
#pragma unroll
        for (int t = 0; t < 5; ++t) {
            bf16x8 bf = *(const bf16x8*)(wp + (t * 16 + m) * 32);
            acc[t] = __builtin_amdgcn_mfma_f32_16x16x32_bf16(af, bf, acc[t], 0, 0, 0);
        }
    }
#pragma unroll
    for (int t = 0; t < 5; ++t)
#pragma unroll
        for (int j = 0; j < 4; ++j)
            ot[wv * 16 + g * 4 + j][t * 16 + m] = f2bf(acc[t][j]);
    __syncthreads();

    int vrows = N_NODES - n0; if (vrows > 64) vrows = 64;
    {   // fp8 writeout: this col-third owns 20 uints of each 64-uint row
        for (int i = tid; i < vrows * 20; i += 256) {
            int r = i / 20, c = i - r * 20;
            uint2 q = *(const uint2*)&ot[r][c * 4];
            float2 p0 = bfp2(q.x), p1 = bfp2(q.y);
            int lo = __builtin_amdgcn_cvt_pk_fp8_f32(p0.x, p0.y, 0, false);
            unsigned int packed = (unsigned int)__builtin_amdgcn_cvt_pk_fp8_f32(p1.x, p1.y, lo, true);
            h8[(size_t)(n0 + r) * 64 + cb / 4 + c] = packed;
        }
        if (third == 0) {  // zero the 4 pad uints per row
            for (int i = tid; i < vrows * 4; i += 256)
                h8[(size_t)(n0 + (i >> 2)) * 64 + 60 + (i & 3)] = 0;
        }
    }
    // al3 for the 2 heads of this col-third (pre-scaled by log2e)
    for (int t = tid; t < vrows * 2; t += 256) {
        int node = t >> 1, hh = t & 1;
        int hd = third * 2 + hh;
        const unsigned short* rp = &ot[node][hh * 40];
        const float* as = a_s + hd * 40;
        const float* ad = a_d + hd * 40;
        float s1 = 0.f, s2 = 0.f;
#pragma unroll
        for (int c = 0; c < 40; c += 2) {
            unsigned int q = *(const unsigned int*)(rp + c);
            float2 p = bfp2(q);
            s1 = fmaf(p.x, as[c], s1);     s2 = fmaf(p.x, ad[c], s2);
            s1 = fmaf(p.y, as[c + 1], s1); s2 = fmaf(p.y, ad[c + 1], s2);
        }
        al_s[(n0 + node) * 6 + hd] = s1 * LOG2E;
        al_d[(n0 + node) * 6 + hd] = s2 * LOG2E;
    }
}

// ---------------- CSR build v3: LDS multisplit, block-private scattered writes ----------------
__global__ __launch_bounds__(256) void bcnt_kernel(const int* __restrict__ ei, int* __restrict__ bcnt) {
    __shared__ int hist[NB];
    const int t = threadIdx.x;
    for (int i = t; i < NB; i += 256) hist[i] = 0;
    __syncthreads();
    const int e0 = blockIdx.x * CHUNK;
    int n = N_EDGES - e0; if (n > CHUNK) n = CHUNK;     // n % 4 == 0 always
    const int4* d4 = (const int4*)(ei + N_EDGES) + (e0 >> 2);
    for (int i = t; i < (n >> 2); i += 256) {
        int4 d = d4[i];
        atomicAdd(&hist[d.x >> 7], 1);
        atomicAdd(&hist[d.y >> 7], 1);
        atomicAdd(&hist[d.z >> 7], 1);
        atomicAdd(&hist[d.w >> 7], 1);
    }
    __syncthreads();
    for (int b = t; b < NB; b += 256)
        if (hist[b]) atomicAdd(&bcnt[b], hist[b]);
}

__global__ void scan391_kernel(const int* __restrict__ bcnt, int* __restrict__ bbase,
                               int* __restrict__ bcur) {
    __shared__ int wtot[8];
    int b = threadIdx.x;              // 512 threads, 8 waves
    int lane = b & 63, w = b >> 6;
    int v = (b < NB) ? bcnt[b] : 0;
    int sc = v;
#pragma unroll
    for (int off = 1; off < 64; off <<= 1) {
        int u = __shfl_up(sc, off);
        if (lane >= off) sc += u;
    }
    if (lane == 63) wtot[w] = sc;
    __syncthreads();
    int add = 0;
    for (int k = 0; k < w; ++k) add += wtot[k];
    int excl = sc - v + add;
    if (b < NB) { bbase[b] = excl; bcur[b * 16] = excl; }
    if (b == 0) bbase[NB] = N_EDGES;
}

__global__ __launch_bounds__(256) void bucket2_kernel(const int* __restrict__ ei,
                                                      int* __restrict__ bcur,
                                                      unsigned int* __restrict__ stage) {
    __shared__ unsigned int vals[CHUNK];   // 32 KB: (dst<<16)|src
    __shared__ int hist[NB];
    __shared__ int cnt2[NB];
    __shared__ int gbase[NB];
    const int t = threadIdx.x;
    for (int i = t; i < NB; i += 256) { hist[i] = 0; cnt2[i] = 0; }
    __syncthreads();
    const int e0 = blockIdx.x * CHUNK;
    int n = N_EDGES - e0; if (n > CHUNK) n = CHUNK;     // n % 4 == 0
    const int4* s4 = (const int4*)ei + (e0 >> 2);
    const int4* d4 = (const int4*)(ei + N_EDGES) + (e0 >> 2);
    for (int i = t; i < (n >> 2); i += 256) {
        int4 s = s4[i], d = d4[i];
        vals[4 * i + 0] = ((unsigned int)d.x << 16) | (unsigned int)s.x;
        vals[4 * i + 1] = ((unsigned int)d.y << 16) | (unsigned int)s.y;
        vals[4 * i + 2] = ((unsigned int)d.z << 16) | (unsigned int)s.z;
        vals[4 * i + 3] = ((unsigned int)d.w << 16) | (unsigned int)s.w;
        atomicAdd(&hist[d.x >> 7], 1);
        atomicAdd(&hist[d.y >> 7], 1);
        atomicAdd(&hist[d.z >> 7], 1);
        atomicAdd(&hist[d.w >> 7], 1);
    }
    __syncthreads();
    for (int b = t; b < NB; b += 256)
        if (hist[b]) gbase[b] = atomicAdd(&bcur[b * 16], hist[b]);
    __syncthreads();
    for (int i = t; i < n; i += 256) {
        unsigned int v = vals[i];
        int b = v >> 23;                                  // dst>>7
        int r = atomicAdd(&cnt2[b], 1);
        stage[gbase[b] + r] = v & 0x7FFFFFu;              // ((dst&127)<<16)|src
    }
}

__global__ __launch_bounds__(256) void place2_kernel(const unsigned int* __restrict__ stage,
                                                     const int* __restrict__ bbase,
                                                     int* __restrict__ rowptr,
                                                     unsigned short* __restrict__ csr) {
    __shared__ int hist[128];
    __shared__ int cur[128];
    __shared__ int wt[2];
    const int b = blockIdx.x;
    const int n0 = b * 128;
    const int t = threadIdx.x;
    const int base = bbase[b];
    const int endp = bbase[b + 1];
    if (t < 128) hist[t] = 0;
    __syncthreads();
    for (int i = base + t; i < endp; i += 256)
        atomicAdd(&hist[stage[i] >> 16], 1);
    __syncthreads();
    int v = 0, sc = 0;
    if (t < 128) {
        v = hist[t];
        int lane = t & 63, w = t >> 6;
        sc = v;
#pragma unroll
        for (int off = 1; off < 64; off <<= 1) {
            int u = __shfl_up(sc, off);
            if (lane >= off) sc += u;
        }
        if (lane == 63) wt[w] = sc;
    }
    __syncthreads();
    if (t < 128) {
        int add = (t >= 64) ? wt[0] : 0;
        int excl = sc - v + add;
        int n = n0 + t;
        if (n <= N_NODES) rowptr[n] = base + excl;   // rowptr[N] emitted by last bucket
        cur[t] = base + excl;
    }
    __syncthreads();
    for (int i = base + t; i < endp; i += 256) {
        unsigned int e = stage[i];
        int pos = atomicAdd(&cur[e >> 16], 1);
        csr[pos] = (unsigned short)(e & 0xFFFFu);
    }
}

// ------- agg layers 1/2 (HC=64): 4 edges/wave (16 lanes x 4ch), dwordx2 gathers -------
__global__ void agg64_kernel(const int* __restrict__ rowptr, const unsigned short* __restrict__ csr_src,
                             const float* __restrict__ al_s, const float* __restrict__ al_d,
                             const unsigned short* __restrict__ hb, const float* __restrict__ b,
                             float* __restrict__ xn) {
    const int node = blockIdx.x * 4 + (threadIdx.x >> 6);   // grid exact: N_NODES % 4 == 0
    const int lane = threadIdx.x & 63;
    const int eg = lane >> 4;          // edge group 0..3
    const int cl = lane & 15;          // channels [4cl, 4cl+4)
    const int c0 = cl * 4;
    const int hd = cl >> 2;            // 16 ch/head, no straddle
    const float ald = al_d[(unsigned)(node * 4 + hd)];
    const int beg = rowptr[node], end = rowptr[node + 1];
    float denom = 0.f, a0 = 0.f, a1 = 0.f, a2 = 0.f, a3 = 0.f;
    if (eg == 0) {   // self loop
        float w = exp2_fast(lrelu02(al_s[(unsigned)(node * 4 + hd)] + ald));
        uint2 q = *(const uint2*)(hb + (unsigned)(node * 64 + c0));
        float2 p0 = bfp2(q.x), p1 = bfp2(q.y);
        denom = w;
        a0 = w * p0.x; a1 = w * p0.y; a2 = w * p1.x; a3 = w * p1.y;
    }
    int j = beg + eg;
    for (; j + 12 < end; j += 16) {    // 4 edges per group per iter (16/wave)
        int s0 = csr_src[j], s1 = csr_src[j + 4], s2 = csr_src[j + 8], s3 = csr_src[j + 12];
        uint2 q0 = *(const uint2*)(hb + (unsigned)(s0 * 64 + c0));
        uint2 q1 = *(const uint2*)(hb + (unsigned)(s1 * 64 + c0));
        uint2 q2 = *(const uint2*)(hb + (unsigned)(s2 * 64 + c0));
        uint2 q3 = *(const uint2*)(hb + (unsigned)(s3 * 64 + c0));
        float w0 = exp2_fast(lrelu02(al_s[(unsigned)(s0 * 4 + hd)] + ald));
        float w1 = exp2_fast(lrelu02(al_s[(unsigned)(s1 * 4 + hd)] + ald));
        float w2 = exp2_fast(lrelu02(al_s[(unsigned)(s2 * 4 + hd)] + ald));
        float w3 = exp2_fast(lrelu02(al_s[(unsigned)(s3 * 4 + hd)] + ald));
        denom += (w0 + w1) + (w2 + w3);
        float2 p;
        p = bfp2(q0.x); a0 = fmaf(w0, p.x, a0); a1 = fmaf(w0, p.y, a1);
        p = bfp2(q0.y); a2 = fmaf(w0, p.x, a2); a3 = fmaf(w0, p.y, a3);
        p = bfp2(q1.x); a0 = fmaf(w1, p.x, a0); a1 = fmaf(w1, p.y, a1);
        p = bfp2(q1.y); a2 = fmaf(w1, p.x, a2); a3 = fmaf(w1, p.y, a3);
        p = bfp2(q2.x); a0 = fmaf(w2, p.x, a0); a1 = fmaf(w2, p.y, a1);
        p = bfp2(q2.y); a2 = fmaf(w2, p.x, a2); a3 = fmaf(w2, p.y, a3);
        p = bfp2(q3.x); a0 = fmaf(w3, p.x, a0); a1 = fmaf(w3, p.y, a1);
        p = bfp2(q3.y); a2 = fmaf(w3, p.x, a2); a3 = fmaf(w3, p.y, a3);
    }
    for (; j < end; j += 4) {
        int s0 = csr_src[j];
        uint2 q0 = *(const uint2*)(hb + (unsigned)(s0 * 64 + c0));
        float w0 = exp2_fast(lrelu02(al_s[(unsigned)(s0 * 4 + hd)] + ald));
        denom += w0;
        float2 p;
        p = bfp2(q0.x); a0 = fmaf(w0, p.x, a0); a1 = fmaf(w0, p.y, a1);
        p = bfp2(q0.y); a2 = fmaf(w0, p.x, a2); a3 = fmaf(w0, p.y, a3);
    }
    // reduce across the 4 edge groups
    denom += __shfl_xor(denom, 16); denom += __shfl_xor(denom, 32);
    a0 += __shfl_xor(a0, 16); a0 += __shfl_xor(a0, 32);
    a1 += __shfl_xor(a1, 16); a1 += __shfl_xor(a1, 32);
    a2 += __shfl_xor(a2, 16); a2 += __shfl_xor(a2, 32);
    a3 += __shfl_xor(a3, 16); a3 += __shfl_xor(a3, 32);
    if (lane < 16) {
        float r = 1.f / denom;
        float4 bv = *(const float4*)(b + c0);
        float4 o;
        o.x = elu1(fmaf(a0, r, bv.x));
        o.y = elu1(fmaf(a1, r, bv.y));
        o.z = elu1(fmaf(a2, r, bv.z));
        o.w = elu1(fmaf(a3, r, bv.w));
        *(float4*)(xn + (unsigned)(node * 64 + c0)) = o;
    }
}

// ------- agg layer 3: 2 edges/wave (32 lanes x 8ch fp8), dwordx2 gathers; fused final -------
__global__ void agg240_kernel(const int* __restrict__ rowptr, const unsigned short* __restrict__ csr_src,
                              const float* __restrict__ al_s, const float* __restrict__ al_d,
                              const unsigned int* __restrict__ h8, const float* __restrict__ b3,
                              float* __restrict__ y) {
    __shared__ float sh[4][240];
    const int wv_id = threadIdx.x >> 6;
    const int node = blockIdx.x * 4 + wv_id;          // grid exact: 12500 blocks
    const int lane = threadIdx.x & 63;
    const int eg = lane >> 5;                         // edge group 0/1
    const int cl = lane & 31;                         // channels [8cl, 8cl+8)
    const int u0 = cl * 2;                            // uint index in 64-uint row
    int hd = cl / 5; if (hd > 5) hd = 5;              // 40 ch/head, 8|40 -> no straddle; pad lanes clamp
    const float ald = al_d[(unsigned)(node * 6 + hd)];
    const int beg = rowptr[node], end = rowptr[node + 1];
    float denom = 0.f;
    float acc[8] = {0.f, 0.f, 0.f, 0.f, 0.f, 0.f, 0.f, 0.f};
    auto acc8 = [&](uint2 q, float w) {
        v2f p0 = __builtin_amdgcn_cvt_pk_f32_fp8((int)q.x, false);
        v2f p1 = __builtin_amdgcn_cvt_pk_f32_fp8((int)q.x, true);
        v2f p2 = __builtin_amdgcn_cvt_pk_f32_fp8((int)q.y, false);
        v2f p3 = __builtin_amdgcn_cvt_pk_f32_fp8((int)q.y, true);
        acc[0] = fmaf(w, p0.x, acc[0]); acc[1] = fmaf(w, p0.y, acc[1]);
        acc[2] = fmaf(w, p1.x, acc[2]); acc[3] = fmaf(w, p1.y, acc[3]);
        acc[4] = fmaf(w, p2.x, acc[4]); acc[5] = fmaf(w, p2.y, acc[5]);
        acc[6] = fmaf(w, p3.x, acc[6]); acc[7] = fmaf(w, p3.y, acc[7]);
    };
    if (eg == 0) {   // self loop
        float w = exp2_fast(lrelu02(al_s[(unsigned)(node * 6 + hd)] + ald));
        uint2 q = *(const uint2*)(h8 + (unsigned)(node * 64) + u0);
        denom = w;
        acc8(q, w);
    }
    int j = beg + eg;
    for (; j + 6 < end; j += 8) {      // 4 edges per group per iter (8/wave)
        int s0 = csr_src[j], s1 = csr_src[j + 2], s2 = csr_src[j + 4], s3 = csr_src[j + 6];
        uint2 q0 = *(const uint2*)(h8 + (unsigned)(s0 * 64) + u0);
        uint2 q1 = *(const uint2*)(h8 + (unsigned)(s1 * 64) + u0);
        uint2 q2 = *(const uint2*)(h8 + (unsigned)(s2 * 64) + u0);
        uint2 q3 = *(const uint2*)(h8 + (unsigned)(s3 * 64) + u0);
        float w0 = exp2_fast(lrelu02(al_s[(unsigned)(s0 * 6 + hd)] + ald));
        float w1 = exp2_fast(lrelu02(al_s[(unsigned)(s1 * 6 + hd)] + ald));
        float w2 = exp2_fast(lrelu02(al_s[(unsigned)(s2 * 6 + hd)] + ald));
        float w3 = exp2_fast(lrelu02(al_s[(unsigned)(s3 * 6 + hd)] + ald));
        denom += (w0 + w1) + (w2 + w3);
        acc8(q0, w0); acc8(q1, w1); acc8(q2, w2); acc8(q3, w3);
    }
    for (; j < end; j += 2) {
        int s0 = csr_src[j];
        uint2 q0 = *(const uint2*)(h8 + (unsigned)(s0 * 64) + u0);
        float w0 = exp2_fast(lrelu02(al_s[(unsigned)(s0 * 6 + hd)] + ald));
        denom += w0;
        acc8(q0, w0);
    }
    // reduce across the 2 edge groups
    denom += __shfl_xor(denom, 32);
#pragma unroll
    for (int i = 0; i < 8; ++i) acc[i] += __shfl_xor(acc[i], 32);
    if (eg == 0 && cl < 30) {
        float r = 1.f / denom;
        float* sp = &sh[wv_id][cl * 8];
#pragma unroll
        for (int i = 0; i < 8; ++i) sp[i] = acc[i] * r;
    }
    __syncthreads();
    float v;
    if (lane < 40) {
        const float* p = sh[wv_id];
        float s = 0.f;
#pragma unroll
        for (int hh = 0; hh < 6; ++hh) s += p[hh * 40 + lane];
        v = elu1(s * (1.f / 6.f) + b3[lane]);
    } else {
        v = -INFINITY;
    }
    float m = v;
#pragma unroll
    for (int o = 32; o > 0; o >>= 1) m = fmaxf(m, __shfl_xor(m, o));
    float ex = (lane < 40) ? __expf(v - m) : 0.f;
    float ssum = ex;
#pragma unroll
    for (int o = 32; o > 0; o >>= 1) ssum += __shfl_xor(ssum, o);
    if (lane < 40) y[(size_t)node * 40 + lane] = v - m - __logf(ssum);
}

extern "C" void kernel_launch(void* const* d_in, const int* in_sizes, int n_in,
                              void* d_out, int out_size, void* d_ws, size_t ws_size,
                              hipStream_t stream) {
    const float* x   = (const float*)d_in[0];
    const int*   ei  = (const int*)d_in[1];   // [2, E]
    const float* W1  = (const float*)d_in[2];
    const float* a1s = (const float*)d_in[3];
    const float* a1d = (const float*)d_in[4];
    const float* b1  = (const float*)d_in[5];
    const float* W2  = (const float*)d_in[6];
    const float* a2s = (const float*)d_in[7];
    const float* a2d = (const float*)d_in[8];
    const float* b2  = (const float*)d_in[9];
    const float* W3  = (const float*)d_in[10];
    const float* a3s = (const float*)d_in[11];
    const float* a3d = (const float*)d_in[12];
    const float* b3  = (const float*)d_in[13];
    float* y = (float*)d_out;

    float* ws = (float*)d_ws;
    unsigned short* h_bf = (unsigned short*)ws;               // 3.2M ushort (layers 1/2)
    float* x_buf   = ws + 1600000;                            // 3,200,000 floats
    float* al_s    = ws + 4800000;                            //   300,000
    float* al_d    = ws + 5100000;                            //   300,000
    unsigned int* h8 = (unsigned int*)(ws + 5400000);         // 3.2M uints (layer-3 fp8, 256B rows)
    int*   rowptr  = (int*)(ws + 8600000);                    //    50,001
    unsigned short* csr_src = (unsigned short*)(ws + 8650008);  // 1.6M ushort
    unsigned int* stage = (unsigned int*)(ws + 9450008);      // 1.6M uint
    int*   bcnt    = (int*)(ws + 11050008);                   //    NB ints
    int*   bbase   = (int*)(ws + 11050400);                   //    NB+1 ints
    int*   bcur    = (int*)(ws + 11050792);                   //    NB*16 ints

    // ---- CSR build v3: LDS-hist -> scan -> multisplit -> private placement ----
    hipMemsetAsync(bcnt, 0, NB * sizeof(int), stream);
    bcnt_kernel<<<NCHUNK, 256, 0, stream>>>(ei, bcnt);
    scan391_kernel<<<1, 512, 0, stream>>>(bcnt, bbase, bcur);
    bucket2_kernel<<<NCHUNK, 256, 0, stream>>>(ei, bcur, stage);
    place2_kernel<<<NB, 256, 0, stream>>>(stage, bbase, rowptr, csr_src);

    const int agg_grid = N_NODES / 4;              // 12500, exact
    const int gemm_gx = (N_NODES + 63) / 64;       // 782 blocks of 64 rows

    // ---- layer 1: 128 -> (4,16) concat ----
    gemm_al_kernel<128><<<gemm_gx, 256, 0, stream>>>(x, W1, a1s, a1d, h_bf, al_s, al_d);
    agg64_kernel<<<agg_grid, 256, 0, stream>>>(rowptr, csr_src, al_s, al_d, h_bf, b1, x_buf);

    // ---- layer 2: 64 -> (4,16) concat ----
    gemm_al_kernel<64><<<gemm_gx, 256, 0, stream>>>(x_buf, W2, a2s, a2d, h_bf, al_s, al_d);
    agg64_kernel<<<agg_grid, 256, 0, stream>>>(rowptr, csr_src, al_s, al_d, h_bf, b2, x_buf);

    // ---- layer 3: 64 -> (6,40) mean; fp8 h; 3 col-blocks of 80 ----
    gemm80_kernel<<<gemm_gx * 3, 256, 0, stream>>>(x_buf, W3, a3s, a3d, h8, al_s, al_d);
    agg240_kernel<<<agg_grid, 256, 0, stream>>>(rowptr, csr_src, al_s, al_d, h8, b3, y);
}